// Round 17
// baseline (5358.400 us; speedup 1.0000x reference)
//
#include <hip/hip_runtime.h>
#include <hip/hip_bf16.h>

#define Bb   64
#define Tt   512
#define INN  256
#define HH   1024
#define OUTN 512

#define MG   16              // batch rows per group
#define NGRP (Bb / MG)       // 4 groups

typedef __attribute__((ext_vector_type(8))) short bf16x8;
typedef __attribute__((ext_vector_type(4))) float f32x4;

__device__ __forceinline__ unsigned short f2b(float f) {
  unsigned u = __float_as_uint(f);
  u += 0x7FFFu + ((u >> 16) & 1u);
  return (unsigned short)(u >> 16);
}

__device__ __forceinline__ unsigned long long cohLoadU64(const unsigned long long* p) {
  return __hip_atomic_load(p, __ATOMIC_RELAXED, __HIP_MEMORY_SCOPE_AGENT);
}
__device__ __forceinline__ void cohStoreU16(unsigned short* p, unsigned short v) {
  __hip_atomic_store(p, v, __ATOMIC_RELAXED, __HIP_MEMORY_SCOPE_AGENT);
}

__device__ __forceinline__ f32x4 splat4(float v) { f32x4 r = {v, v, v, v}; return r; }

union U16 { unsigned long long u[2]; bf16x8 v; };

// Coherent (MALL-served, L1+L2-bypass) pipelined 16B load, literal offset.
// Valid only after a following counted s_waitcnt vmcnt (VMW). Counted waits
// stay correct with older pending stores in the queue (they complete first,
// only adding to the completions counted).
#define ALOADO(d, p, OFF)                                                     \
  asm volatile("global_load_dwordx4 %0, %1, off offset:" #OFF " sc0 sc1"      \
               : "=v"(d) : "v"(p))
#define VMW(N)                                                                \
  do {                                                                        \
    asm volatile("s_waitcnt vmcnt(" #N ")" ::: "memory");                     \
    __builtin_amdgcn_sched_barrier(0);                                        \
  } while (0)

// fp32 -> bf16 (RNE), vectorized x4
__global__ void cvt4(const float* __restrict__ in, unsigned short* __restrict__ out, int n4) {
  int i = blockIdx.x * blockDim.x + threadIdx.x;
  if (i >= n4) return;
  float4 v = ((const float4*)in)[i];
  ushort4 o;
  o.x = f2b(v.x); o.y = f2b(v.y); o.z = f2b(v.z); o.w = f2b(v.w);
  ((ushort4*)out)[i] = o;
}

__global__ void addv(const float* __restrict__ a, const float* __restrict__ b,
                     float* __restrict__ o, int n) {
  int i = blockIdx.x * blockDim.x + threadIdx.x;
  if (i < n) o[i] = a[i] + b[i];
}

// Fill with bf16 NaN sentinel 0x7FC0 (unreachable by tanh / finite math).
__global__ void nanfill(uint4* __restrict__ p, int n16) {
  int i = blockIdx.x * blockDim.x + threadIdx.x;
  if (i < n16) {
    uint4 v; v.x = v.y = v.z = v.w = 0x7FC07FC0u;
    p[i] = v;
  }
}

// One K=1024 GEMM phase with DATA-IS-FLAG readiness: coherent A loads, MFMA
// into trial accumulators, NaN in the 4 output f32s (propagated from any
// sentinel A element through IEEE f32 accumulation) => data not ready =>
// retry. Clean => commit accin + s. No producer drains/flags anywhere.
// W (B-operand): 32 bf16x8 in AGPRs (laundered "+a" each attempt).
#define ISSUE8(V, O0, O1, O2, O3, O4, O5, O6, O7)                             \
  ALOADO(V##0, Ap, O0); ALOADO(V##1, Ap, O1); ALOADO(V##2, Ap, O2);           \
  ALOADO(V##3, Ap, O3); ALOADO(V##4, Ap, O4); ALOADO(V##5, Ap, O5);           \
  ALOADO(V##6, Ap, O6); ALOADO(V##7, Ap, O7);
#define COMP8(V, WI)                                                          \
  acc  = __builtin_amdgcn_mfma_f32_16x16x32_bf16(V##0, w[(WI)+0], acc,  0,0,0);\
  acc2 = __builtin_amdgcn_mfma_f32_16x16x32_bf16(V##1, w[(WI)+1], acc2, 0,0,0);\
  acc  = __builtin_amdgcn_mfma_f32_16x16x32_bf16(V##2, w[(WI)+2], acc,  0,0,0);\
  acc2 = __builtin_amdgcn_mfma_f32_16x16x32_bf16(V##3, w[(WI)+3], acc2, 0,0,0);\
  acc  = __builtin_amdgcn_mfma_f32_16x16x32_bf16(V##4, w[(WI)+4], acc,  0,0,0);\
  acc2 = __builtin_amdgcn_mfma_f32_16x16x32_bf16(V##5, w[(WI)+5], acc2, 0,0,0);\
  acc  = __builtin_amdgcn_mfma_f32_16x16x32_bf16(V##6, w[(WI)+6], acc,  0,0,0);\
  acc2 = __builtin_amdgcn_mfma_f32_16x16x32_bf16(V##7, w[(WI)+7], acc2, 0,0,0);

__device__ __forceinline__ f32x4 kphase_nan(const short* Ap, bf16x8* w,
                                            f32x4 accin, int& dead) {
#pragma clang loop unroll(disable)
  for (int att = 0; att < 20000; ++att) {
#pragma unroll
    for (int c = 0; c < 32; ++c) asm volatile("" : "+a"(w[c]));  // pin AGPRs
    f32x4 acc = {0, 0, 0, 0}, acc2 = {0, 0, 0, 0};
    bf16x8 A_0, A_1, A_2, A_3, A_4, A_5, A_6, A_7;
    bf16x8 B_0, B_1, B_2, B_3, B_4, B_5, B_6, B_7;
    bf16x8 C_0, C_1, C_2, C_3, C_4, C_5, C_6, C_7;
    bf16x8 D_0, D_1, D_2, D_3, D_4, D_5, D_6, D_7;
    ISSUE8(A_,    0,   64,  128,  192,  256,  320,  384,  448)
    ISSUE8(B_,  512,  576,  640,  704,  768,  832,  896,  960)
    ISSUE8(C_, 1024, 1088, 1152, 1216, 1280, 1344, 1408, 1472)
    ISSUE8(D_, 1536, 1600, 1664, 1728, 1792, 1856, 1920, 1984)
    VMW(24); COMP8(A_,  0)
    VMW(16); COMP8(B_,  8)
    VMW(8);  COMP8(C_, 16)
    VMW(0);  COMP8(D_, 24)
    f32x4 s = acc + acc2;
    const int bad = (s[0] != s[0]) || (s[1] != s[1]) ||
                    (s[2] != s[2]) || (s[3] != s[3]);
    if (!__any(bad)) return accin + s;
    if (dead) return accin + s;       // already bailed once: accept garbage
    __builtin_amdgcn_s_sleep(2);
  }
  dead = 1;                           // fail loud (NaN output), never hang
  return accin;
}

// 2-stage persistent RNN, NO FLAGS — data readiness via NaN sentinel.
// 192 blocks x 256 thr (4 waves). Blocks 0..63: L0 (4 grp x 16 blk, 64 cols
// each; wave = 16 cols). Blocks 64..191: L1 (4 grp x 32 blk, 32 cols each;
// waves 0-1 = Wh1-kphase on P2[t-1], waves 2-3 = Wx1-kphase on P0[t];
// combined through 4KB double-buffered LDS + one barrier per step).
//  L0: h1_t = tanh(Wh0 h1_{t-1} + Wx0 x_t + b0)  -> P0[t]   (write-once)
//  L1: h2_t = tanh(Wh1 h2_{t-1} + Wx1 h1_t + b1) -> P2[t]   (write-once)
__global__ __launch_bounds__(256) void rnn2(
    const __hip_bfloat16* __restrict__ xs,                        // [B][T][IN]
    const __hip_bfloat16* __restrict__ Wx0, const __hip_bfloat16* __restrict__ Wh0,
    const __hip_bfloat16* __restrict__ Wx1, const __hip_bfloat16* __restrict__ Wh1,
    const float* __restrict__ b0s, const float* __restrict__ b1s,
    __hip_bfloat16* __restrict__ P0, __hip_bfloat16* __restrict__ P2)
{
  __shared__ float xl[2][2][64][4];   // [parity][xp-wave][lane][4]
  const int tid = threadIdx.x;
  const int l   = tid & 63;
  const int wv  = tid >> 6;           // 0..3
  const int bid = blockIdx.x;
  const int fr  = l & 15;
  const int lh  = l >> 4;
  const int rb  = lh << 2;
  int dead = 0;
  unsigned short* P0u = (unsigned short*)P0;
  unsigned short* P2u = (unsigned short*)P2;

  if (bid < 64) {
    // ---------------- L0 ----------------
    const int j = bid & 15, g = bid >> 4;
    const int rowA = g * MG;
    const int ccol = j * 64 + wv * 16 + fr;
    const long laneA = (long)(rowA + fr) * HH + (lh << 3);

    const short* Wgrow = (const short*)Wh0 + (long)ccol * HH + (lh << 3);
    bf16x8 w[32];
#pragma unroll
    for (int c = 0; c < 32; ++c) w[c] = *(const bf16x8*)(Wgrow + (c << 5));
#pragma unroll
    for (int c = 0; c < 32; ++c) asm volatile("" : "+a"(w[c]));

    const float bias = b0s[ccol];
    const short* xrow = (const short*)xs + (long)(rowA + fr) * (Tt * INN) + (lh << 3);
    const short* Wx0row = (const short*)Wx0 + (long)ccol * INN + (lh << 3);
    bf16x8 wx[8];
#pragma unroll
    for (int c = 0; c < 8; ++c) wx[c] = *(const bf16x8*)(Wx0row + (c << 5));
#pragma unroll
    for (int c = 0; c < 8; ++c) asm volatile("" : "+a"(wx[c]));

    f32x4 acc = splat4(bias);
#pragma unroll
    for (int c = 0; c < 8; ++c) {       // xp0 for t=0
      bf16x8 a = *(const bf16x8*)(xrow + (c << 5));
      acc = __builtin_amdgcn_mfma_f32_16x16x32_bf16(a, wx[c], acc, 0, 0, 0);
    }
    for (int t = 0; t < Tt; ++t) {
      if (t > 0)
        acc = kphase_nan((const short*)P0 + (long)(t - 1) * (Bb * HH) + laneA,
                         w, acc, dead);
      const long cb = ((long)t * Bb + rowA + rb) * HH + ccol;
#pragma unroll
      for (int r = 0; r < 4; ++r)
        cohStoreU16(P0u + cb + (long)r * HH, f2b(tanhf(acc[r])));
      // no drain, no flag — consumers detect via NaN sentinel
      if (t + 1 < Tt) {                 // next xp0 while stores fly
        acc = splat4(bias);
        const short* xr = xrow + (t + 1) * INN;
#pragma unroll
        for (int c = 0; c < 8; ++c) {
          bf16x8 a = *(const bf16x8*)(xr + (c << 5));
          acc = __builtin_amdgcn_mfma_f32_16x16x32_bf16(a, wx[c], acc, 0, 0, 0);
        }
      }
    }
  } else {
    // ---------------- L1 ----------------
    const int idx = bid - 64;
    const int j = idx & 31, g = idx >> 5;
    const int rowA = g * MG;
    const int isXP = (wv >= 2);
    const int pair = isXP ? (wv - 2) : wv;       // 0..1
    const int ccol = j * 32 + pair * 16 + fr;
    const long laneA = (long)(rowA + fr) * HH + (lh << 3);

    const short* Wgrow = (const short*)(isXP ? Wx1 : Wh1) + (long)ccol * HH + (lh << 3);
    bf16x8 w[32];
#pragma unroll
    for (int c = 0; c < 32; ++c) w[c] = *(const bf16x8*)(Wgrow + (c << 5));
#pragma unroll
    for (int c = 0; c < 32; ++c) asm volatile("" : "+a"(w[c]));

    const float bias = b1s[ccol];

    for (int t = 0; t < Tt; ++t) {
      f32x4 whs = {0, 0, 0, 0};
      if (isXP) {
        f32x4 s = kphase_nan((const short*)P0 + (long)t * (Bb * HH) + laneA,
                             w, splat4(bias), dead);
        *(float4*)&xl[t & 1][pair][l][0] = *(float4*)&s;
      } else if (t > 0) {
        whs = kphase_nan((const short*)P2 + (long)(t - 1) * (Bb * HH) + laneA,
                         w, whs, dead);
      }
      __syncthreads();
      if (!isXP) {
        const float* xp = &xl[t & 1][pair][l][0];
        const long cb = ((long)t * Bb + rowA + rb) * HH + ccol;
#pragma unroll
        for (int r = 0; r < 4; ++r)
          cohStoreU16(P2u + cb + (long)r * HH, f2b(tanhf(whs[r] + xp[r])));
      }
    }
  }
}

// fc: out[64][512] = h2_last @ Wfc^T + bfc (coherent A reads).
__global__ void fc_kernel(const __hip_bfloat16* __restrict__ A,
                          const __hip_bfloat16* __restrict__ W,
                          const float* __restrict__ bias,
                          float* __restrict__ C)
{
  const int l   = threadIdx.x;
  const int m0  = blockIdx.x << 4;
  const int n0  = blockIdx.y << 6;
  const int r16 = l & 15;
  const int lh  = l >> 4;

  const unsigned long long* Au =
      (const unsigned long long*)((const short*)A + (long)(m0 + r16) * HH);
  const short* Wp = (const short*)W;
  const long w0 = (long)(n0 + r16) * HH + (lh << 3);
  const long wS = (long)HH << 4;

  f32x4 acc0 = {0,0,0,0}, acc1 = {0,0,0,0}, acc2 = {0,0,0,0}, acc3 = {0,0,0,0};
  for (int kc = 0; kc < HH; kc += 32) {
    U16 a;
    a.u[0] = cohLoadU64(Au + (kc >> 2) + (lh << 1));
    a.u[1] = cohLoadU64(Au + (kc >> 2) + (lh << 1) + 1);
    bf16x8 b0 = *(const bf16x8*)(Wp + w0 +          kc);
    bf16x8 b1 = *(const bf16x8*)(Wp + w0 + wS     + kc);
    bf16x8 b2 = *(const bf16x8*)(Wp + w0 + 2 * wS + kc);
    bf16x8 b3 = *(const bf16x8*)(Wp + w0 + 3 * wS + kc);
    acc0 = __builtin_amdgcn_mfma_f32_16x16x32_bf16(a.v, b0, acc0, 0, 0, 0);
    acc1 = __builtin_amdgcn_mfma_f32_16x16x32_bf16(a.v, b1, acc1, 0, 0, 0);
    acc2 = __builtin_amdgcn_mfma_f32_16x16x32_bf16(a.v, b2, acc2, 0, 0, 0);
    acc3 = __builtin_amdgcn_mfma_f32_16x16x32_bf16(a.v, b3, acc3, 0, 0, 0);
  }
  const int col = l & 15;
  const int rbb = (l >> 4) << 2;
#define FCEP(FIDX, ACC)                                                       \
  { const int n = n0 + (FIDX << 4) + col;                                     \
    _Pragma("unroll")                                                         \
    for (int r = 0; r < 4; ++r)                                               \
      C[(long)(m0 + rbb + r) * OUTN + n] = ACC[r] + bias[n]; }
  FCEP(0, acc0) FCEP(1, acc1) FCEP(2, acc2) FCEP(3, acc3)
#undef FCEP
}

extern "C" void kernel_launch(void* const* d_in, const int* in_sizes, int n_in,
                              void* d_out, int out_size, void* d_ws, size_t ws_size,
                              hipStream_t stream)
{
  const float* x   = (const float*)d_in[0];
  const float* Wx0 = (const float*)d_in[1];
  const float* bx0 = (const float*)d_in[2];
  const float* Wh0 = (const float*)d_in[3];
  const float* bh0 = (const float*)d_in[4];
  const float* Wx1 = (const float*)d_in[5];
  const float* bx1 = (const float*)d_in[6];
  const float* Wh1 = (const float*)d_in[7];
  const float* bh1 = (const float*)d_in[8];
  const float* Wfc = (const float*)d_in[9];
  const float* bfc = (const float*)d_in[10];

  char* ws = (char*)d_ws;
  const long SZ_XBF = (long)Bb * Tt * INN * 2;
  const long SZ_P   = (long)Bb * Tt * HH  * 2;
  __hip_bfloat16* xbf   = (__hip_bfloat16*)(ws);
  __hip_bfloat16* P0    = (__hip_bfloat16*)(ws + SZ_XBF);          // h1 [T][B][H]
  __hip_bfloat16* P2    = (__hip_bfloat16*)(ws + SZ_XBF + SZ_P);   // h2 [T][B][H]
  __hip_bfloat16* Wx0b  = (__hip_bfloat16*)(ws + SZ_XBF + 2 * SZ_P);
  __hip_bfloat16* Wh0b  = (__hip_bfloat16*)((char*)Wx0b + (long)HH * INN * 2);
  __hip_bfloat16* Wx1b  = (__hip_bfloat16*)((char*)Wh0b + (long)HH * HH * 2);
  __hip_bfloat16* Wh1b  = (__hip_bfloat16*)((char*)Wx1b + (long)HH * HH * 2);
  __hip_bfloat16* Wfcb  = (__hip_bfloat16*)((char*)Wh1b + (long)HH * HH * 2);
  float*          b0sum = (float*)((char*)Wfcb + (long)OUTN * HH * 2);
  float*          b1sum = (float*)((char*)b0sum + HH * 4);

  {
    int n4;
    n4 = (Bb * Tt * INN) / 4; cvt4<<<(n4 + 255) / 256, 256, 0, stream>>>(x,   (unsigned short*)xbf,  n4);
    n4 = (HH * INN) / 4;      cvt4<<<(n4 + 255) / 256, 256, 0, stream>>>(Wx0, (unsigned short*)Wx0b, n4);
    n4 = (HH * HH) / 4;       cvt4<<<(n4 + 255) / 256, 256, 0, stream>>>(Wh0, (unsigned short*)Wh0b, n4);
    n4 = (HH * HH) / 4;       cvt4<<<(n4 + 255) / 256, 256, 0, stream>>>(Wx1, (unsigned short*)Wx1b, n4);
    n4 = (HH * HH) / 4;       cvt4<<<(n4 + 255) / 256, 256, 0, stream>>>(Wh1, (unsigned short*)Wh1b, n4);
    n4 = (OUTN * HH) / 4;     cvt4<<<(n4 + 255) / 256, 256, 0, stream>>>(Wfc, (unsigned short*)Wfcb, n4);
    addv<<<4, 256, 0, stream>>>(bx0, bh0, b0sum, HH);
    addv<<<4, 256, 0, stream>>>(bx1, bh1, b1sum, HH);
    // re-sentinel both h-buffers EVERY launch (graph-replay safe)
    const int n16 = (int)(SZ_P / 16);
    nanfill<<<(n16 + 255) / 256, 256, 0, stream>>>((uint4*)P0, n16);
    nanfill<<<(n16 + 255) / 256, 256, 0, stream>>>((uint4*)P2, n16);
  }

  rnn2<<<dim3(192), 256, 0, stream>>>(
      xbf, Wx0b, Wh0b, Wx1b, Wh1b, b0sum, b1sum, P0, P2);

  fc_kernel<<<dim3(Bb / 16, OUTN / 64), 64, 0, stream>>>(
      P2 + (long)(Tt - 1) * Bb * HH, Wfcb, bfc, (float*)d_out);
}

// Round 18
// 3130.615 us; speedup vs baseline: 1.7116x; 1.7116x over previous
//
#include <hip/hip_runtime.h>
#include <hip/hip_bf16.h>

#define Bb   64
#define Tt   512
#define INN  256
#define HH   1024
#define OUTN 512

#define MG   16              // batch rows per group
#define NGRP (Bb / MG)       // 4 groups

typedef __attribute__((ext_vector_type(8))) short bf16x8;
typedef __attribute__((ext_vector_type(4))) float f32x4;

__device__ __forceinline__ unsigned short f2b(float f) {
  unsigned u = __float_as_uint(f);
  u += 0x7FFFu + ((u >> 16) & 1u);
  return (unsigned short)(u >> 16);
}

__device__ __forceinline__ unsigned long long cohLoadU64(const unsigned long long* p) {
  return __hip_atomic_load(p, __ATOMIC_RELAXED, __HIP_MEMORY_SCOPE_AGENT);
}
__device__ __forceinline__ void cohStoreU16(unsigned short* p, unsigned short v) {
  __hip_atomic_store(p, v, __ATOMIC_RELAXED, __HIP_MEMORY_SCOPE_AGENT);
}

__device__ __forceinline__ f32x4 splat4(float v) { f32x4 r = {v, v, v, v}; return r; }

union U16 { unsigned long long u[2]; bf16x8 v; };

// Coherent (MALL-served, L1+L2-bypass) pipelined 16B load, literal offset.
#define ALOADO(d, p, OFF)                                                     \
  asm volatile("global_load_dwordx4 %0, %1, off offset:" #OFF " sc0 sc1"      \
               : "=v"(d) : "v"(p))
#define VMW(N)                                                                \
  do {                                                                        \
    asm volatile("s_waitcnt vmcnt(" #N ")" ::: "memory");                     \
    __builtin_amdgcn_sched_barrier(0);                                        \
  } while (0)

// fp32 -> bf16 (RNE), vectorized x4
__global__ void cvt4(const float* __restrict__ in, unsigned short* __restrict__ out, int n4) {
  int i = blockIdx.x * blockDim.x + threadIdx.x;
  if (i >= n4) return;
  float4 v = ((const float4*)in)[i];
  ushort4 o;
  o.x = f2b(v.x); o.y = f2b(v.y); o.z = f2b(v.z); o.w = f2b(v.w);
  ((ushort4*)out)[i] = o;
}

__global__ void addv(const float* __restrict__ a, const float* __restrict__ b,
                     float* __restrict__ o, int n) {
  int i = blockIdx.x * blockDim.x + threadIdx.x;
  if (i < n) o[i] = a[i] + b[i];
}

// Fill with bf16 NaN sentinel 0x7FC0 (unreachable by tanh / finite math).
__global__ void nanfill(uint4* __restrict__ p, int n16) {
  int i = blockIdx.x * blockDim.x + threadIdx.x;
  if (i < n16) {
    uint4 v; v.x = v.y = v.z = v.w = 0x7FC07FC0u;
    p[i] = v;
  }
}

// Probe-wait: lane l polls producer-wave l's CANARY (the element that wave
// stores LAST in program order). One 2-byte coherent load per iteration —
// flag-poll cost, but no producer drain/flag needed. Completion order of the
// producer's earlier stores is NOT guaranteed by the canary — the NaN-checked
// kphase below is the correctness backstop.
__device__ __forceinline__ void probe_wait(const unsigned short* p) {
#pragma clang loop unroll(disable)
  for (int g = 0; g < 3000000; ++g) {
    unsigned short v;
    asm volatile("global_load_ushort %0, %1, off sc0 sc1\n\ts_waitcnt vmcnt(0)"
                 : "=v"(v) : "v"(p) : "memory");
    if (__all((int)(v != 0x7FC0u))) return;
    __builtin_amdgcn_s_sleep(1);
  }
  // exhaust -> fall through; kphase_nan backstop will bail loudly
}

// One K=1024 GEMM phase with NaN-backstop readiness: coherent A loads, MFMA
// into trial accumulators; NaN in any output f32 => some A element was still
// sentinel => retry. W: 32 bf16x8 in AGPRs (laundered "+a" each attempt).
#define ISSUE8(V, O0, O1, O2, O3, O4, O5, O6, O7)                             \
  ALOADO(V##0, Ap, O0); ALOADO(V##1, Ap, O1); ALOADO(V##2, Ap, O2);           \
  ALOADO(V##3, Ap, O3); ALOADO(V##4, Ap, O4); ALOADO(V##5, Ap, O5);           \
  ALOADO(V##6, Ap, O6); ALOADO(V##7, Ap, O7);
#define COMP8(V, WI)                                                          \
  acc  = __builtin_amdgcn_mfma_f32_16x16x32_bf16(V##0, w[(WI)+0], acc,  0,0,0);\
  acc2 = __builtin_amdgcn_mfma_f32_16x16x32_bf16(V##1, w[(WI)+1], acc2, 0,0,0);\
  acc  = __builtin_amdgcn_mfma_f32_16x16x32_bf16(V##2, w[(WI)+2], acc,  0,0,0);\
  acc2 = __builtin_amdgcn_mfma_f32_16x16x32_bf16(V##3, w[(WI)+3], acc2, 0,0,0);\
  acc  = __builtin_amdgcn_mfma_f32_16x16x32_bf16(V##4, w[(WI)+4], acc,  0,0,0);\
  acc2 = __builtin_amdgcn_mfma_f32_16x16x32_bf16(V##5, w[(WI)+5], acc2, 0,0,0);\
  acc  = __builtin_amdgcn_mfma_f32_16x16x32_bf16(V##6, w[(WI)+6], acc,  0,0,0);\
  acc2 = __builtin_amdgcn_mfma_f32_16x16x32_bf16(V##7, w[(WI)+7], acc2, 0,0,0);

__device__ __forceinline__ f32x4 kphase_nan(const short* Ap, bf16x8* w,
                                            f32x4 accin, int& dead) {
#pragma clang loop unroll(disable)
  for (int att = 0; att < 20000; ++att) {
#pragma unroll
    for (int c = 0; c < 32; ++c) asm volatile("" : "+a"(w[c]));  // pin AGPRs
    f32x4 acc = {0, 0, 0, 0}, acc2 = {0, 0, 0, 0};
    bf16x8 A_0, A_1, A_2, A_3, A_4, A_5, A_6, A_7;
    bf16x8 B_0, B_1, B_2, B_3, B_4, B_5, B_6, B_7;
    bf16x8 C_0, C_1, C_2, C_3, C_4, C_5, C_6, C_7;
    bf16x8 D_0, D_1, D_2, D_3, D_4, D_5, D_6, D_7;
    ISSUE8(A_,    0,   64,  128,  192,  256,  320,  384,  448)
    ISSUE8(B_,  512,  576,  640,  704,  768,  832,  896,  960)
    ISSUE8(C_, 1024, 1088, 1152, 1216, 1280, 1344, 1408, 1472)
    ISSUE8(D_, 1536, 1600, 1664, 1728, 1792, 1856, 1920, 1984)
    VMW(24); COMP8(A_,  0)
    VMW(16); COMP8(B_,  8)
    VMW(8);  COMP8(C_, 16)
    VMW(0);  COMP8(D_, 24)
    f32x4 s = acc + acc2;
    const int bad = (s[0] != s[0]) || (s[1] != s[1]) ||
                    (s[2] != s[2]) || (s[3] != s[3]);
    if (!__any(bad)) return accin + s;
    if (dead) return accin + s;       // already bailed once: accept garbage
    __builtin_amdgcn_s_sleep(2);
  }
  dead = 1;                           // fail loud (NaN output), never hang
  return accin;
}

// 2-stage persistent RNN, NO FLAGS — probe canaries + NaN backstop.
// 192 blocks x 256 thr (4 waves). Blocks 0..63: L0 (4 grp x 16 blk, 64 cols
// each; wave = 16 cols). Blocks 64..191: L1 (4 grp x 32 blk, 32 cols each;
// waves 0-1 = Wh1-kphase on P2[t-1], waves 2-3 = Wx1-kphase on P0[t];
// combined via 4KB double-buffered LDS + one barrier per step).
//  L0: h1_t = tanh(Wh0 h1_{t-1} + Wx0 x_t + b0)  -> P0[t]   (write-once)
//  L1: h2_t = tanh(Wh1 h2_{t-1} + Wx1 h1_t + b1) -> P2[t]   (write-once)
// Canary of producer wave w: row rowA+15, col = w's col-base (stored last).
//  P0 producers: 4 waves/block, 16 blocks -> col0(w) = (w>>2)*64 + (w&3)*16
//  P2 producers: 2 wh-waves/block, 32 blocks -> col2(w) = (w>>1)*32 + (w&1)*16
__global__ __launch_bounds__(256) void rnn2(
    const __hip_bfloat16* __restrict__ xs,                        // [B][T][IN]
    const __hip_bfloat16* __restrict__ Wx0, const __hip_bfloat16* __restrict__ Wh0,
    const __hip_bfloat16* __restrict__ Wx1, const __hip_bfloat16* __restrict__ Wh1,
    const float* __restrict__ b0s, const float* __restrict__ b1s,
    __hip_bfloat16* __restrict__ P0, __hip_bfloat16* __restrict__ P2)
{
  __shared__ float xl[2][2][64][4];   // [parity][xp-wave][lane][4]
  const int tid = threadIdx.x;
  const int l   = tid & 63;
  const int wv  = tid >> 6;           // 0..3
  const int bid = blockIdx.x;
  const int fr  = l & 15;
  const int lh  = l >> 4;
  const int rb  = lh << 2;
  int dead = 0;
  unsigned short* P0u = (unsigned short*)P0;
  unsigned short* P2u = (unsigned short*)P2;
  const int col0l = ((l >> 2) << 6) + ((l & 3) << 4);   // P0 canary col (lane l)
  const int col2l = ((l >> 1) << 5) + ((l & 1) << 4);   // P2 canary col (lane l)
  const long BT = (long)Bb * HH;

  if (bid < 64) {
    // ---------------- L0 ----------------
    const int j = bid & 15, g = bid >> 4;
    const int rowA = g * MG;
    const int ccol = j * 64 + wv * 16 + fr;
    const long laneA = (long)(rowA + fr) * HH + (lh << 3);
    const unsigned short* can0 = P0u + (long)(rowA + 15) * HH + col0l;

    const short* Wgrow = (const short*)Wh0 + (long)ccol * HH + (lh << 3);
    bf16x8 w[32];
#pragma unroll
    for (int c = 0; c < 32; ++c) w[c] = *(const bf16x8*)(Wgrow + (c << 5));
#pragma unroll
    for (int c = 0; c < 32; ++c) asm volatile("" : "+a"(w[c]));

    const float bias = b0s[ccol];
    const short* xrow = (const short*)xs + (long)(rowA + fr) * (Tt * INN) + (lh << 3);
    const short* Wx0row = (const short*)Wx0 + (long)ccol * INN + (lh << 3);
    bf16x8 wx[8];
#pragma unroll
    for (int c = 0; c < 8; ++c) wx[c] = *(const bf16x8*)(Wx0row + (c << 5));
#pragma unroll
    for (int c = 0; c < 8; ++c) asm volatile("" : "+a"(wx[c]));

    f32x4 acc = splat4(bias);
#pragma unroll
    for (int c = 0; c < 8; ++c) {       // xp0 for t=0
      bf16x8 a = *(const bf16x8*)(xrow + (c << 5));
      acc = __builtin_amdgcn_mfma_f32_16x16x32_bf16(a, wx[c], acc, 0, 0, 0);
    }
    for (int t = 0; t < Tt; ++t) {
      if (t > 0) {
        probe_wait(can0 + (long)(t - 1) * BT);
        acc = kphase_nan((const short*)P0 + (long)(t - 1) * BT + laneA,
                         w, acc, dead);
      }
      const long cb = ((long)t * Bb + rowA + rb) * HH + ccol;
#pragma unroll
      for (int r = 0; r < 4; ++r)
        cohStoreU16(P0u + cb + (long)r * HH, f2b(tanhf(acc[r])));
      // no drain, no flag — canary (row 15 store, issued last) + NaN backstop
      if (t + 1 < Tt) {                 // next xp0 while stores fly
        acc = splat4(bias);
        const short* xr = xrow + (t + 1) * INN;
#pragma unroll
        for (int c = 0; c < 8; ++c) {
          bf16x8 a = *(const bf16x8*)(xr + (c << 5));
          acc = __builtin_amdgcn_mfma_f32_16x16x32_bf16(a, wx[c], acc, 0, 0, 0);
        }
      }
    }
  } else {
    // ---------------- L1 ----------------
    const int idx = bid - 64;
    const int j = idx & 31, g = idx >> 5;
    const int rowA = g * MG;
    const int isXP = (wv >= 2);
    const int pair = isXP ? (wv - 2) : wv;       // 0..1
    const int ccol = j * 32 + pair * 16 + fr;
    const long laneA = (long)(rowA + fr) * HH + (lh << 3);
    const unsigned short* can0 = P0u + (long)(rowA + 15) * HH + col0l;
    const unsigned short* can2 = P2u + (long)(rowA + 15) * HH + col2l;

    const short* Wgrow = (const short*)(isXP ? Wx1 : Wh1) + (long)ccol * HH + (lh << 3);
    bf16x8 w[32];
#pragma unroll
    for (int c = 0; c < 32; ++c) w[c] = *(const bf16x8*)(Wgrow + (c << 5));
#pragma unroll
    for (int c = 0; c < 32; ++c) asm volatile("" : "+a"(w[c]));

    const float bias = b1s[ccol];

    for (int t = 0; t < Tt; ++t) {
      f32x4 whs = {0, 0, 0, 0};
      if (isXP) {
        probe_wait(can0 + (long)t * BT);
        f32x4 s = kphase_nan((const short*)P0 + (long)t * BT + laneA,
                             w, splat4(bias), dead);
        *(float4*)&xl[t & 1][pair][l][0] = *(float4*)&s;
      } else if (t > 0) {
        probe_wait(can2 + (long)(t - 1) * BT);
        whs = kphase_nan((const short*)P2 + (long)(t - 1) * BT + laneA,
                         w, whs, dead);
      }
      __syncthreads();
      if (!isXP) {
        const float* xp = &xl[t & 1][pair][l][0];
        const long cb = ((long)t * Bb + rowA + rb) * HH + ccol;
#pragma unroll
        for (int r = 0; r < 4; ++r)
          cohStoreU16(P2u + cb + (long)r * HH, f2b(tanhf(whs[r] + xp[r])));
      }
    }
  }
}

// fc: out[64][512] = h2_last @ Wfc^T + bfc (coherent A reads).
__global__ void fc_kernel(const __hip_bfloat16* __restrict__ A,
                          const __hip_bfloat16* __restrict__ W,
                          const float* __restrict__ bias,
                          float* __restrict__ C)
{
  const int l   = threadIdx.x;
  const int m0  = blockIdx.x << 4;
  const int n0  = blockIdx.y << 6;
  const int r16 = l & 15;
  const int lh  = l >> 4;

  const unsigned long long* Au =
      (const unsigned long long*)((const short*)A + (long)(m0 + r16) * HH);
  const short* Wp = (const short*)W;
  const long w0 = (long)(n0 + r16) * HH + (lh << 3);
  const long wS = (long)HH << 4;

  f32x4 acc0 = {0,0,0,0}, acc1 = {0,0,0,0}, acc2 = {0,0,0,0}, acc3 = {0,0,0,0};
  for (int kc = 0; kc < HH; kc += 32) {
    U16 a;
    a.u[0] = cohLoadU64(Au + (kc >> 2) + (lh << 1));
    a.u[1] = cohLoadU64(Au + (kc >> 2) + (lh << 1) + 1);
    bf16x8 b0 = *(const bf16x8*)(Wp + w0 +          kc);
    bf16x8 b1 = *(const bf16x8*)(Wp + w0 + wS     + kc);
    bf16x8 b2 = *(const bf16x8*)(Wp + w0 + 2 * wS + kc);
    bf16x8 b3 = *(const bf16x8*)(Wp + w0 + 3 * wS + kc);
    acc0 = __builtin_amdgcn_mfma_f32_16x16x32_bf16(a.v, b0, acc0, 0, 0, 0);
    acc1 = __builtin_amdgcn_mfma_f32_16x16x32_bf16(a.v, b1, acc1, 0, 0, 0);
    acc2 = __builtin_amdgcn_mfma_f32_16x16x32_bf16(a.v, b2, acc2, 0, 0, 0);
    acc3 = __builtin_amdgcn_mfma_f32_16x16x32_bf16(a.v, b3, acc3, 0, 0, 0);
  }
  const int col = l & 15;
  const int rbb = (l >> 4) << 2;
#define FCEP(FIDX, ACC)                                                       \
  { const int n = n0 + (FIDX << 4) + col;                                     \
    _Pragma("unroll")                                                         \
    for (int r = 0; r < 4; ++r)                                               \
      C[(long)(m0 + rbb + r) * OUTN + n] = ACC[r] + bias[n]; }
  FCEP(0, acc0) FCEP(1, acc1) FCEP(2, acc2) FCEP(3, acc3)
#undef FCEP
}

extern "C" void kernel_launch(void* const* d_in, const int* in_sizes, int n_in,
                              void* d_out, int out_size, void* d_ws, size_t ws_size,
                              hipStream_t stream)
{
  const float* x   = (const float*)d_in[0];
  const float* Wx0 = (const float*)d_in[1];
  const float* bx0 = (const float*)d_in[2];
  const float* Wh0 = (const float*)d_in[3];
  const float* bh0 = (const float*)d_in[4];
  const float* Wx1 = (const float*)d_in[5];
  const float* bx1 = (const float*)d_in[6];
  const float* Wh1 = (const float*)d_in[7];
  const float* bh1 = (const float*)d_in[8];
  const float* Wfc = (const float*)d_in[9];
  const float* bfc = (const float*)d_in[10];

  char* ws = (char*)d_ws;
  const long SZ_XBF = (long)Bb * Tt * INN * 2;
  const long SZ_P   = (long)Bb * Tt * HH  * 2;
  __hip_bfloat16* xbf   = (__hip_bfloat16*)(ws);
  __hip_bfloat16* P0    = (__hip_bfloat16*)(ws + SZ_XBF);          // h1 [T][B][H]
  __hip_bfloat16* P2    = (__hip_bfloat16*)(ws + SZ_XBF + SZ_P);   // h2 [T][B][H]
  __hip_bfloat16* Wx0b  = (__hip_bfloat16*)(ws + SZ_XBF + 2 * SZ_P);
  __hip_bfloat16* Wh0b  = (__hip_bfloat16*)((char*)Wx0b + (long)HH * INN * 2);
  __hip_bfloat16* Wx1b  = (__hip_bfloat16*)((char*)Wh0b + (long)HH * HH * 2);
  __hip_bfloat16* Wh1b  = (__hip_bfloat16*)((char*)Wx1b + (long)HH * HH * 2);
  __hip_bfloat16* Wfcb  = (__hip_bfloat16*)((char*)Wh1b + (long)HH * HH * 2);
  float*          b0sum = (float*)((char*)Wfcb + (long)OUTN * HH * 2);
  float*          b1sum = (float*)((char*)b0sum + HH * 4);

  {
    int n4;
    n4 = (Bb * Tt * INN) / 4; cvt4<<<(n4 + 255) / 256, 256, 0, stream>>>(x,   (unsigned short*)xbf,  n4);
    n4 = (HH * INN) / 4;      cvt4<<<(n4 + 255) / 256, 256, 0, stream>>>(Wx0, (unsigned short*)Wx0b, n4);
    n4 = (HH * HH) / 4;       cvt4<<<(n4 + 255) / 256, 256, 0, stream>>>(Wh0, (unsigned short*)Wh0b, n4);
    n4 = (HH * HH) / 4;       cvt4<<<(n4 + 255) / 256, 256, 0, stream>>>(Wx1, (unsigned short*)Wx1b, n4);
    n4 = (HH * HH) / 4;       cvt4<<<(n4 + 255) / 256, 256, 0, stream>>>(Wh1, (unsigned short*)Wh1b, n4);
    n4 = (OUTN * HH) / 4;     cvt4<<<(n4 + 255) / 256, 256, 0, stream>>>(Wfc, (unsigned short*)Wfcb, n4);
    addv<<<4, 256, 0, stream>>>(bx0, bh0, b0sum, HH);
    addv<<<4, 256, 0, stream>>>(bx1, bh1, b1sum, HH);
    // re-sentinel both h-buffers EVERY launch (graph-replay safe)
    const int n16 = (int)(SZ_P / 16);
    nanfill<<<(n16 + 255) / 256, 256, 0, stream>>>((uint4*)P0, n16);
    nanfill<<<(n16 + 255) / 256, 256, 0, stream>>>((uint4*)P2, n16);
  }

  rnn2<<<dim3(192), 256, 0, stream>>>(
      xbf, Wx0b, Wh0b, Wx1b, Wh1b, b0sum, b1sum, P0, P2);

  fc_kernel<<<dim3(Bb / 16, OUTN / 64), 64, 0, stream>>>(
      P2 + (long)(Tt - 1) * Bb * HH, Wfcb, bfc, (float*)d_out);
}